// Round 1
// baseline (734.785 us; speedup 1.0000x reference)
//
#include <hip/hip_runtime.h>
#include <hip/hip_bf16.h>
#include <math.h>

#define N_TOKENS 32768
#define HIDDEN   2048
#define NEXP     8
#define H4       (HIDDEN / 4)            // 512 float4 per row
#define BLOCK    1024                    // 16 waves
#define WPB      (BLOCK / 64)            // waves per block = 16
#define TOK_PER_WAVE 4
#define GRID     (N_TOKENS / (WPB * TOK_PER_WAVE))   // 512 blocks

#define SCORES_OFF 0
#define IDX_OFF    (N_TOKENS * 2)        // 65536
#define HIST_OFF   (N_TOKENS * 4)        // 131072

__global__ void zero_hist_kernel(float* out) {
    if (threadIdx.x < NEXP) out[HIST_OFF + threadIdx.x] = 0.0f;
}

__device__ __forceinline__ void emit_token(const double* acc, int t,
                                           float* __restrict__ out, int* cnt) {
    // top-2 with lowest-index tie-break (strict >), matching jax.lax.top_k
    double b1 = acc[0]; int i1 = 0;
    double b2 = -1.0e300; int i2 = 0;
#pragma unroll
    for (int e = 1; e < NEXP; ++e) {
        double v = acc[e];
        if (v > b1)      { b2 = b1; i2 = i1; b1 = v; i1 = e; }
        else if (v > b2) { b2 = v;  i2 = e; }
    }
    // softmax over the two (b1 >= b2): s0 = 1/(1+e^(b2-b1))
    float d  = (float)(b2 - b1);
    float e1 = expf(d);
    float s0 = 1.0f / (1.0f + e1);
    float s1 = e1 * s0;

    float2 sc; sc.x = s0; sc.y = s1;
    float2 ix; ix.x = (float)i1; ix.y = (float)i2;
    *reinterpret_cast<float2*>(out + SCORES_OFF + 2 * t) = sc;
    *reinterpret_cast<float2*>(out + IDX_OFF    + 2 * t) = ix;

#pragma unroll
    for (int e = 0; e < NEXP; ++e) cnt[e] += (i1 == e) + (i2 == e);
}

__global__ __launch_bounds__(BLOCK, 4) void router_kernel(
        const float* __restrict__ x, const float* __restrict__ W,
        float* __restrict__ out) {
    __shared__ float4 wlds[NEXP * H4];   // 64 KiB: W staged as float4, [e][h4]

    const int tid = threadIdx.x;
    const float4* Wv = reinterpret_cast<const float4*>(W);
#pragma unroll
    for (int i = 0; i < (NEXP * H4) / BLOCK; ++i)
        wlds[tid + i * BLOCK] = Wv[tid + i * BLOCK];
    __syncthreads();

    const int wave = tid >> 6;
    const int lane = tid & 63;
    const int gw   = blockIdx.x * WPB + wave;     // 0..8191

    int cnt[NEXP] = {0, 0, 0, 0, 0, 0, 0, 0};

#pragma unroll 1
    for (int p = 0; p < TOK_PER_WAVE / 2; ++p) {
        const int t0 = gw * TOK_PER_WAVE + 2 * p;
        const float4* xa = reinterpret_cast<const float4*>(x) + (size_t)t0 * H4;
        const float4* xb = xa + H4;

        double acc0[NEXP], acc1[NEXP];
#pragma unroll
        for (int e = 0; e < NEXP; ++e) { acc0[e] = 0.0; acc1[e] = 0.0; }

#pragma unroll
        for (int k = 0; k < H4 / 64; ++k) {       // 8 iterations
            const float4 a = xa[lane + k * 64];
            const float4 b = xb[lane + k * 64];
#pragma unroll
            for (int e = 0; e < NEXP; ++e) {
                const float4 w = wlds[e * H4 + lane + k * 64];
                const double w0 = w.x, w1 = w.y, w2 = w.z, w3 = w.w;
                acc0[e] = fma(w0, (double)a.x, acc0[e]);
                acc0[e] = fma(w1, (double)a.y, acc0[e]);
                acc0[e] = fma(w2, (double)a.z, acc0[e]);
                acc0[e] = fma(w3, (double)a.w, acc0[e]);
                acc1[e] = fma(w0, (double)b.x, acc1[e]);
                acc1[e] = fma(w1, (double)b.y, acc1[e]);
                acc1[e] = fma(w2, (double)b.z, acc1[e]);
                acc1[e] = fma(w3, (double)b.w, acc1[e]);
            }
        }

        // wave-wide butterfly reduction of 16 doubles
#pragma unroll
        for (int m = 1; m < 64; m <<= 1) {
#pragma unroll
            for (int e = 0; e < NEXP; ++e) {
                acc0[e] += __shfl_xor(acc0[e], m, 64);
                acc1[e] += __shfl_xor(acc1[e], m, 64);
            }
        }

        if (lane == 0) {
            emit_token(acc0, t0,     out, cnt);
            emit_token(acc1, t0 + 1, out, cnt);
        }
    }

    // block histogram: reuse wlds as scratch after all waves finish reading W
    __syncthreads();
    float* h = reinterpret_cast<float*>(wlds);
    if (tid < NEXP) h[tid] = 0.0f;
    __syncthreads();
    if (lane == 0) {
#pragma unroll
        for (int e = 0; e < NEXP; ++e)
            if (cnt[e]) atomicAdd(&h[e], (float)cnt[e]);
    }
    __syncthreads();
    if (tid < NEXP) atomicAdd(&out[HIST_OFF + tid], h[tid]);
}

extern "C" void kernel_launch(void* const* d_in, const int* in_sizes, int n_in,
                              void* d_out, int out_size, void* d_ws, size_t ws_size,
                              hipStream_t stream) {
    const float* x = (const float*)d_in[0];
    const float* W = (const float*)d_in[1];
    float* out = (float*)d_out;

    zero_hist_kernel<<<1, 64, 0, stream>>>(out);
    router_kernel<<<GRID, BLOCK, 0, stream>>>(x, W, out);
}

// Round 2
// 82.275 us; speedup vs baseline: 8.9308x; 8.9308x over previous
//
#include <hip/hip_runtime.h>
#include <hip/hip_bf16.h>
#include <math.h>

#define N_TOKENS 32768
#define HIDDEN   2048
#define NEXP     8
#define H4       (HIDDEN / 4)            // 512 float4 per row
#define BLOCK    1024                    // 16 waves
#define WPB      (BLOCK / 64)            // waves per block = 16
#define TOK_PER_WAVE 4
#define GRID     (N_TOKENS / (WPB * TOK_PER_WAVE))   // 512 blocks

#define SCORES_OFF 0
#define IDX_OFF    (N_TOKENS * 2)        // 65536
#define HIST_OFF   (N_TOKENS * 4)        // 131072

__global__ void zero_hist_kernel(float* out) {
    if (threadIdx.x < NEXP) out[HIST_OFF + threadIdx.x] = 0.0f;
}

__device__ __forceinline__ void emit_token(const double* acc, int t,
                                           float* __restrict__ out, int* cnt) {
    // top-2 with lowest-index tie-break (strict >), matching jax.lax.top_k
    double b1 = acc[0]; int i1 = 0;
    double b2 = -1.0e300; int i2 = 0;
#pragma unroll
    for (int e = 1; e < NEXP; ++e) {
        double v = acc[e];
        if (v > b1)      { b2 = b1; i2 = i1; b1 = v; i1 = e; }
        else if (v > b2) { b2 = v;  i2 = e; }
    }
    // softmax over the two (b1 >= b2): s0 = 1/(1+e^(b2-b1))
    float d  = (float)(b2 - b1);
    float e1 = expf(d);
    float s0 = 1.0f / (1.0f + e1);
    float s1 = e1 * s0;

    float2 sc; sc.x = s0; sc.y = s1;
    float2 ix; ix.x = (float)i1; ix.y = (float)i2;
    *reinterpret_cast<float2*>(out + SCORES_OFF + 2 * t) = sc;
    *reinterpret_cast<float2*>(out + IDX_OFF    + 2 * t) = ix;

#pragma unroll
    for (int e = 0; e < NEXP; ++e) cnt[e] += (i1 == e) + (i2 == e);
}

__global__ __launch_bounds__(BLOCK, 4) void router_kernel(
        const float* __restrict__ x, const float* __restrict__ W,
        float* __restrict__ out) {
    __shared__ float4 wlds[NEXP * H4];   // 64 KiB: W staged as float4, [e][h4]

    const int tid = threadIdx.x;
    const float4* Wv = reinterpret_cast<const float4*>(W);
#pragma unroll
    for (int i = 0; i < (NEXP * H4) / BLOCK; ++i)
        wlds[tid + i * BLOCK] = Wv[tid + i * BLOCK];
    __syncthreads();

    const int wave = tid >> 6;
    const int lane = tid & 63;
    const int gw   = blockIdx.x * WPB + wave;     // 0..8191

    int cnt[NEXP] = {0, 0, 0, 0, 0, 0, 0, 0};

    // one token at a time per wave: acc footprint = 16 VGPRs, so no spills
#pragma unroll 1
    for (int p = 0; p < TOK_PER_WAVE; ++p) {
        const int t = gw * TOK_PER_WAVE + p;
        const float4* xt = reinterpret_cast<const float4*>(x) + (size_t)t * H4;

        double acc[NEXP];
#pragma unroll
        for (int e = 0; e < NEXP; ++e) acc[e] = 0.0;

#pragma unroll 4
        for (int k = 0; k < H4 / 64; ++k) {       // 8 iterations, 4 loads in flight
            const float4 a = xt[lane + k * 64];
#pragma unroll
            for (int e = 0; e < NEXP; ++e) {
                const float4 w = wlds[e * H4 + lane + k * 64];
                acc[e] = fma((double)w.x, (double)a.x, acc[e]);
                acc[e] = fma((double)w.y, (double)a.y, acc[e]);
                acc[e] = fma((double)w.z, (double)a.z, acc[e]);
                acc[e] = fma((double)w.w, (double)a.w, acc[e]);
            }
        }

        // wave-wide butterfly reduction of 8 doubles
#pragma unroll
        for (int m = 1; m < 64; m <<= 1) {
#pragma unroll
            for (int e = 0; e < NEXP; ++e)
                acc[e] += __shfl_xor(acc[e], m, 64);
        }

        if (lane == 0) emit_token(acc, t, out, cnt);
    }

    // block histogram: reuse wlds as scratch after all waves finish reading W
    __syncthreads();
    float* h = reinterpret_cast<float*>(wlds);
    if (tid < NEXP) h[tid] = 0.0f;
    __syncthreads();
    if (lane == 0) {
#pragma unroll
        for (int e = 0; e < NEXP; ++e)
            if (cnt[e]) atomicAdd(&h[e], (float)cnt[e]);
    }
    __syncthreads();
    if (tid < NEXP) atomicAdd(&out[HIST_OFF + tid], h[tid]);
}

extern "C" void kernel_launch(void* const* d_in, const int* in_sizes, int n_in,
                              void* d_out, int out_size, void* d_ws, size_t ws_size,
                              hipStream_t stream) {
    const float* x = (const float*)d_in[0];
    const float* W = (const float*)d_in[1];
    float* out = (float*)d_out;

    zero_hist_kernel<<<1, 64, 0, stream>>>(out);
    router_kernel<<<GRID, BLOCK, 0, stream>>>(x, W, out);
}

// Round 3
// 74.812 us; speedup vs baseline: 9.8218x; 1.0998x over previous
//
#include <hip/hip_runtime.h>
#include <hip/hip_bf16.h>
#include <math.h>

#define N_TOKENS 32768
#define HIDDEN   2048
#define NEXP     8
#define H4       (HIDDEN / 4)            // 512 float4 per row
#define BLOCK    1024                    // 16 waves
#define WPB      (BLOCK / 64)            // waves per block = 16
#define TOK_PER_WAVE 4
#define GRID     (N_TOKENS / (WPB * TOK_PER_WAVE))   // 512 blocks

#define SCORES_OFF 0
#define IDX_OFF    (N_TOKENS * 2)        // 65536
#define HIST_OFF   (N_TOKENS * 4)        // 131072

__global__ void zero_hist_kernel(float* out) {
    if (threadIdx.x < NEXP) out[HIST_OFF + threadIdx.x] = 0.0f;
}

__device__ __forceinline__ void emit_token(const double* acc, int t,
                                           float* __restrict__ out, int* cnt) {
    // top-2 with lowest-index tie-break (strict >), matching jax.lax.top_k
    double b1 = acc[0]; int i1 = 0;
    double b2 = -1.0e300; int i2 = 0;
#pragma unroll
    for (int e = 1; e < NEXP; ++e) {
        double v = acc[e];
        if (v > b1)      { b2 = b1; i2 = i1; b1 = v; i1 = e; }
        else if (v > b2) { b2 = v;  i2 = e; }
    }
    // softmax over the two (b1 >= b2): s0 = 1/(1+e^(b2-b1))
    float d  = (float)(b2 - b1);
    float e1 = expf(d);
    float s0 = 1.0f / (1.0f + e1);
    float s1 = e1 * s0;

    float2 sc; sc.x = s0; sc.y = s1;
    float2 ix; ix.x = (float)i1; ix.y = (float)i2;
    *reinterpret_cast<float2*>(out + SCORES_OFF + 2 * t) = sc;
    *reinterpret_cast<float2*>(out + IDX_OFF    + 2 * t) = ix;

#pragma unroll
    for (int e = 0; e < NEXP; ++e) cnt[e] += (i1 == e) + (i2 == e);
}

__global__ __launch_bounds__(BLOCK, 4) void router_kernel(
        const float* __restrict__ x, const float* __restrict__ W,
        float* __restrict__ out) {
    __shared__ float4 wlds[NEXP * H4];   // 64 KiB: W staged as float4, [e][h4]

    const int tid = threadIdx.x;
    const float4* Wv = reinterpret_cast<const float4*>(W);
#pragma unroll
    for (int i = 0; i < (NEXP * H4) / BLOCK; ++i)
        wlds[tid + i * BLOCK] = Wv[tid + i * BLOCK];
    __syncthreads();

    const int wave = tid >> 6;
    const int lane = tid & 63;
    const int gw   = blockIdx.x * WPB + wave;     // 0..8191

    int cnt[NEXP] = {0, 0, 0, 0, 0, 0, 0, 0};

    // 2 tokens per pass: W float4 read once from LDS, used for both tokens.
    // acc = 32 VGPRs (f64 x 16); unroll 2 keeps live set ~72 < 128 cap.
#pragma unroll 1
    for (int p = 0; p < TOK_PER_WAVE / 2; ++p) {
        const int t0 = gw * TOK_PER_WAVE + 2 * p;
        const float4* xa = reinterpret_cast<const float4*>(x) + (size_t)t0 * H4;
        const float4* xb = xa + H4;

        double acc0[NEXP], acc1[NEXP];
#pragma unroll
        for (int e = 0; e < NEXP; ++e) { acc0[e] = 0.0; acc1[e] = 0.0; }

#pragma unroll 2
        for (int k = 0; k < H4 / 64; ++k) {       // 8 iterations
            const float4 a = xa[lane + k * 64];
            const float4 b = xb[lane + k * 64];
#pragma unroll
            for (int e = 0; e < NEXP; ++e) {
                const float4 w = wlds[e * H4 + lane + k * 64];
                // f32 dot4, then one f64 accumulate per chunk:
                // chunk err ~1e-7 << ref's own f32 err (3e-7) << min top-2 gap (~6e-5)
                float s0 = w.x * a.x;
                s0 = fmaf(w.y, a.y, s0);
                s0 = fmaf(w.z, a.z, s0);
                s0 = fmaf(w.w, a.w, s0);
                acc0[e] += (double)s0;
                float s1 = w.x * b.x;
                s1 = fmaf(w.y, b.y, s1);
                s1 = fmaf(w.z, b.z, s1);
                s1 = fmaf(w.w, b.w, s1);
                acc1[e] += (double)s1;
            }
        }

        // wave-wide butterfly reduction of 16 doubles
#pragma unroll
        for (int m = 1; m < 64; m <<= 1) {
#pragma unroll
            for (int e = 0; e < NEXP; ++e) {
                acc0[e] += __shfl_xor(acc0[e], m, 64);
                acc1[e] += __shfl_xor(acc1[e], m, 64);
            }
        }

        if (lane == 0) {
            emit_token(acc0, t0,     out, cnt);
            emit_token(acc1, t0 + 1, out, cnt);
        }
    }

    // block histogram: reuse wlds as scratch after all waves finish reading W
    __syncthreads();
    float* h = reinterpret_cast<float*>(wlds);
    if (tid < NEXP) h[tid] = 0.0f;
    __syncthreads();
    if (lane == 0) {
#pragma unroll
        for (int e = 0; e < NEXP; ++e)
            if (cnt[e]) atomicAdd(&h[e], (float)cnt[e]);
    }
    __syncthreads();
    if (tid < NEXP) atomicAdd(&out[HIST_OFF + tid], h[tid]);
}

extern "C" void kernel_launch(void* const* d_in, const int* in_sizes, int n_in,
                              void* d_out, int out_size, void* d_ws, size_t ws_size,
                              hipStream_t stream) {
    const float* x = (const float*)d_in[0];
    const float* W = (const float*)d_in[1];
    float* out = (float*)d_out;

    zero_hist_kernel<<<1, 64, 0, stream>>>(out);
    router_kernel<<<GRID, BLOCK, 0, stream>>>(x, W, out);
}